// Round 1
// baseline (1305.251 us; speedup 1.0000x reference)
//
#include <hip/hip_runtime.h>

#define N_NODES 100000
#define N_EDGES 800000
// D_IN=128, D_H=64, N_CLS=40, L=4, ALPHA=0.1, THETA=0.5

__device__ inline float4 f4zero() { return make_float4(0.f, 0.f, 0.f, 0.f); }

__device__ inline float4 fma4(float s, float4 w, float4 a) {
    a.x = fmaf(s, w.x, a.x); a.y = fmaf(s, w.y, a.y);
    a.z = fmaf(s, w.z, a.z); a.w = fmaf(s, w.w, a.w);
    return a;
}

__device__ inline float4 relu4(float4 a) {
    a.x = fmaxf(a.x, 0.f); a.y = fmaxf(a.y, 0.f);
    a.z = fmaxf(a.z, 0.f); a.w = fmaxf(a.w, 0.f);
    return a;
}

__device__ inline float f4c(const float4& v, int i) {
    return reinterpret_cast<const float*>(&v)[i];
}

// ---------------- CSR build ----------------

__global__ __launch_bounds__(256) void k_zero_cnt(int* __restrict__ cnt) {
    int i = blockIdx.x * 256 + threadIdx.x;
    if (i < N_NODES) cnt[i] = 0;
}

__global__ __launch_bounds__(256) void k_count(const int* __restrict__ col, int* __restrict__ cnt) {
    int e = blockIdx.x * 256 + threadIdx.x;
    if (e < N_EDGES) atomicAdd(&cnt[col[e]], 1);
}

__global__ __launch_bounds__(256) void k_dinv(const int* __restrict__ cnt, float* __restrict__ dinv) {
    int i = blockIdx.x * 256 + threadIdx.x;
    if (i < N_NODES) dinv[i] = rsqrtf((float)cnt[i] + 1.0f);  // +1 self loop; deg >= 1 always
}

// block-wise exclusive scan: 1024 items per 256-thread block
__global__ __launch_bounds__(256) void k_scan1(const int* __restrict__ cnt, int* __restrict__ starts,
                                               int* __restrict__ bsum) {
    __shared__ int sh[256];
    int t = threadIdx.x, b = blockIdx.x;
    int base = b * 1024 + t * 4;
    int c0 = 0, c1 = 0, c2 = 0, c3 = 0;
    if (base + 3 < N_NODES) {
        int4 v = *reinterpret_cast<const int4*>(cnt + base);
        c0 = v.x; c1 = v.y; c2 = v.z; c3 = v.w;
    } else {
        if (base + 0 < N_NODES) c0 = cnt[base + 0];
        if (base + 1 < N_NODES) c1 = cnt[base + 1];
        if (base + 2 < N_NODES) c2 = cnt[base + 2];
    }
    int s = c0 + c1 + c2 + c3;
    sh[t] = s;
    __syncthreads();
    for (int off = 1; off < 256; off <<= 1) {
        int add = (t >= off) ? sh[t - off] : 0;
        __syncthreads();
        sh[t] += add;
        __syncthreads();
    }
    int excl = sh[t] - s;
    if (t == 255) bsum[b] = sh[t];
    int p = excl;
    if (base + 0 < N_NODES) starts[base + 0] = p; p += c0;
    if (base + 1 < N_NODES) starts[base + 1] = p; p += c1;
    if (base + 2 < N_NODES) starts[base + 2] = p; p += c2;
    if (base + 3 < N_NODES) starts[base + 3] = p;
}

__global__ __launch_bounds__(128) void k_scan2(int* __restrict__ bsum, int nb) {
    __shared__ int sh[128];
    int t = threadIdx.x;
    int v = (t < nb) ? bsum[t] : 0;
    sh[t] = v;
    __syncthreads();
    for (int off = 1; off < 128; off <<= 1) {
        int add = (t >= off) ? sh[t - off] : 0;
        __syncthreads();
        sh[t] += add;
        __syncthreads();
    }
    if (t < nb) bsum[t] = sh[t] - v;  // exclusive block offsets, in place
}

__global__ __launch_bounds__(256) void k_scan3(int* __restrict__ starts, int* __restrict__ cursor,
                                               const int* __restrict__ bsum) {
    int t = threadIdx.x, b = blockIdx.x;
    int off = bsum[b];
    int base = b * 1024 + t * 4;
#pragma unroll
    for (int j = 0; j < 4; ++j) {
        int i = base + j;
        if (i < N_NODES) {
            int v = starts[i] + off;
            starts[i] = v;
            cursor[i] = v;
        }
    }
    if (b == 0 && t == 0) starts[N_NODES] = N_EDGES;
}

__global__ __launch_bounds__(256) void k_fill(const int* __restrict__ row, const int* __restrict__ col,
                                              int* __restrict__ cursor, int* __restrict__ csr) {
    int e = blockIdx.x * 256 + threadIdx.x;
    if (e < N_EDGES) {
        int c = col[e];
        int p = atomicAdd(&cursor[c], 1);
        csr[p] = row[e];
    }
}

// ---------------- fc0: h = relu(x @ W0 + b0), 128 -> 64 ----------------
// block = 256 threads = 64 nodes; thread: 4 nodes (g) x 4 dims (q, float4)
__global__ __launch_bounds__(256) void k_fc0(const float* __restrict__ x, const float* __restrict__ w,
                                             const float* __restrict__ bias, float* __restrict__ out) {
    __shared__ float4 ws[2048];  // 128 x 16 float4 = 32KB
    const float4* wg = reinterpret_cast<const float4*>(w);
#pragma unroll
    for (int i = 0; i < 8; ++i) ws[threadIdx.x + 256 * i] = wg[threadIdx.x + 256 * i];
    __syncthreads();
    int q = threadIdx.x & 15, g = threadIdx.x >> 4;
    int nbase = blockIdx.x * 64 + g * 4;
    float4 bv = reinterpret_cast<const float4*>(bias)[q];
    float4 a0 = bv, a1 = bv, a2 = bv, a3 = bv;
    const float4* x4 = reinterpret_cast<const float4*>(x);
    bool ok0 = nbase + 0 < N_NODES, ok1 = nbase + 1 < N_NODES;
    bool ok2 = nbase + 2 < N_NODES, ok3 = nbase + 3 < N_NODES;
    for (int kk = 0; kk < 32; ++kk) {
        float4 x0v = ok0 ? x4[(size_t)(nbase + 0) * 32 + kk] : f4zero();
        float4 x1v = ok1 ? x4[(size_t)(nbase + 1) * 32 + kk] : f4zero();
        float4 x2v = ok2 ? x4[(size_t)(nbase + 2) * 32 + kk] : f4zero();
        float4 x3v = ok3 ? x4[(size_t)(nbase + 3) * 32 + kk] : f4zero();
#pragma unroll
        for (int dk = 0; dk < 4; ++dk) {
            float4 w4 = ws[(kk * 4 + dk) * 16 + q];
            a0 = fma4(f4c(x0v, dk), w4, a0);
            a1 = fma4(f4c(x1v, dk), w4, a1);
            a2 = fma4(f4c(x2v, dk), w4, a2);
            a3 = fma4(f4c(x3v, dk), w4, a3);
        }
    }
    float4* o4 = reinterpret_cast<float4*>(out);
    if (ok0) o4[(size_t)(nbase + 0) * 16 + q] = relu4(a0);
    if (ok1) o4[(size_t)(nbase + 1) * 16 + q] = relu4(a1);
    if (ok2) o4[(size_t)(nbase + 2) * 16 + q] = relu4(a2);
    if (ok3) o4[(size_t)(nbase + 3) * 16 + q] = relu4(a3);
}

// ---------------- propagation: out[c] = dinv[c] * (dinv[c]*h[c] + sum dinv[src]*h[src]) ----------------
// MODE 0: out = relu(prop)        (first conv; also becomes x0)
// MODE 1: out = 0.9*prop + 0.1*x0 (alpha combine)
template <int MODE>
__global__ __launch_bounds__(256) void k_prop(const float* __restrict__ hin, float* __restrict__ hout,
                                              const float* __restrict__ x0, const float* __restrict__ dinv,
                                              const int* __restrict__ starts, const int* __restrict__ csr) {
    int t = blockIdx.x * 256 + threadIdx.x;
    int node = t >> 4, q = t & 15;  // 16 lanes per node, float4 per lane
    if (node >= N_NODES) return;
    float dc = dinv[node];
    const float4* h4 = reinterpret_cast<const float4*>(hin);
    float4 hv = h4[(size_t)node * 16 + q];
    float4 acc = make_float4(dc * hv.x, dc * hv.y, dc * hv.z, dc * hv.w);
    int s = starts[node], e = starts[node + 1];
    for (int p = s; p < e; ++p) {
        int src = csr[p];
        float ds = dinv[src];
        float4 v = h4[(size_t)src * 16 + q];
        acc = fma4(ds, v, acc);
    }
    float4 o;
    if (MODE == 0) {
        o = relu4(make_float4(dc * acc.x, dc * acc.y, dc * acc.z, dc * acc.w));
    } else {
        float4 xv = reinterpret_cast<const float4*>(x0)[(size_t)node * 16 + q];
        o.x = fmaf(0.9f * dc, acc.x, 0.1f * xv.x);
        o.y = fmaf(0.9f * dc, acc.y, 0.1f * xv.y);
        o.z = fmaf(0.9f * dc, acc.z, 0.1f * xv.z);
        o.w = fmaf(0.9f * dc, acc.w, 0.1f * xv.w);
    }
    reinterpret_cast<float4*>(hout)[(size_t)node * 16 + q] = o;
}

// ---------------- conv layer: h = relu((1-b)*m + b*(m @ W)), 64x64 ----------------
__global__ __launch_bounds__(256) void k_conv(const float* __restrict__ m, const float* __restrict__ w,
                                              float beta, float* __restrict__ out) {
    __shared__ float4 ws[1024];  // 64 x 16 float4 = 16KB
    const float4* wg = reinterpret_cast<const float4*>(w);
#pragma unroll
    for (int i = 0; i < 4; ++i) ws[threadIdx.x + 256 * i] = wg[threadIdx.x + 256 * i];
    __syncthreads();
    int q = threadIdx.x & 15, g = threadIdx.x >> 4;
    int nbase = blockIdx.x * 64 + g * 4;
    float4 a0 = f4zero(), a1 = f4zero(), a2 = f4zero(), a3 = f4zero();
    const float4* m4 = reinterpret_cast<const float4*>(m);
    bool ok0 = nbase + 0 < N_NODES, ok1 = nbase + 1 < N_NODES;
    bool ok2 = nbase + 2 < N_NODES, ok3 = nbase + 3 < N_NODES;
    for (int kk = 0; kk < 16; ++kk) {
        float4 m0v = ok0 ? m4[(size_t)(nbase + 0) * 16 + kk] : f4zero();
        float4 m1v = ok1 ? m4[(size_t)(nbase + 1) * 16 + kk] : f4zero();
        float4 m2v = ok2 ? m4[(size_t)(nbase + 2) * 16 + kk] : f4zero();
        float4 m3v = ok3 ? m4[(size_t)(nbase + 3) * 16 + kk] : f4zero();
#pragma unroll
        for (int dk = 0; dk < 4; ++dk) {
            float4 w4 = ws[(kk * 4 + dk) * 16 + q];
            a0 = fma4(f4c(m0v, dk), w4, a0);
            a1 = fma4(f4c(m1v, dk), w4, a1);
            a2 = fma4(f4c(m2v, dk), w4, a2);
            a3 = fma4(f4c(m3v, dk), w4, a3);
        }
    }
    float omb = 1.0f - beta;
    float4* o4 = reinterpret_cast<float4*>(out);
#pragma unroll
    for (int i = 0; i < 4; ++i) {
        if (nbase + i >= N_NODES) break;
        float4 acc = (i == 0) ? a0 : (i == 1) ? a1 : (i == 2) ? a2 : a3;
        float4 mv = m4[(size_t)(nbase + i) * 16 + q];
        float4 r;
        r.x = fmaf(omb, mv.x, beta * acc.x);
        r.y = fmaf(omb, mv.y, beta * acc.y);
        r.z = fmaf(omb, mv.z, beta * acc.z);
        r.w = fmaf(omb, mv.w, beta * acc.w);
        o4[(size_t)(nbase + i) * 16 + q] = relu4(r);
    }
}

// ---------------- fc1: out = h @ W1 + b1, 64 -> 40 (no relu) ----------------
__global__ __launch_bounds__(256) void k_fc1(const float* __restrict__ h, const float* __restrict__ w,
                                             const float* __restrict__ bias, float* __restrict__ out) {
    __shared__ float4 ws[640];  // 64 x 10 float4 = 10.24KB
    const float4* wg = reinterpret_cast<const float4*>(w);
    for (int i = threadIdx.x; i < 640; i += 256) ws[i] = wg[i];
    __syncthreads();
    int tg = blockIdx.x * 256 + threadIdx.x;
    int n = tg / 10, q = tg % 10;
    if (n >= N_NODES) return;
    float4 acc = reinterpret_cast<const float4*>(bias)[q];
    const float4* h4 = reinterpret_cast<const float4*>(h);
    for (int kk = 0; kk < 16; ++kk) {
        float4 hv = h4[(size_t)n * 16 + kk];
#pragma unroll
        for (int dk = 0; dk < 4; ++dk) {
            float4 w4 = ws[(kk * 4 + dk) * 10 + q];
            acc = fma4(f4c(hv, dk), w4, acc);
        }
    }
    reinterpret_cast<float4*>(out)[(size_t)n * 10 + q] = acc;
}

// ---------------- launch ----------------

extern "C" void kernel_launch(void* const* d_in, const int* in_sizes, int n_in,
                              void* d_out, int out_size, void* d_ws, size_t ws_size,
                              hipStream_t stream) {
    const float* x      = (const float*)d_in[0];
    const int*   ei     = (const int*)d_in[1];
    const float* fc0_w  = (const float*)d_in[2];
    const float* fc0_b  = (const float*)d_in[3];
    const float* fc1_w  = (const float*)d_in[4];
    const float* fc1_b  = (const float*)d_in[5];
    const float* conv_w = (const float*)d_in[6];
    const int* row = ei;
    const int* col = ei + N_EDGES;

    char* ws = (char*)d_ws;
    size_t off = 0;
    auto alloc = [&](size_t bytes) -> void* {
        void* p = ws + off;
        off += (bytes + 255) & ~(size_t)255;
        return p;
    };
    float* dinv   = (float*)alloc((size_t)N_NODES * 4);
    int*   cnt    = (int*)alloc((size_t)N_NODES * 4);
    int*   starts = (int*)alloc((size_t)(N_NODES + 1) * 4);
    int*   cursor = (int*)alloc((size_t)(N_NODES + 1) * 4);
    int*   csr    = (int*)alloc((size_t)N_EDGES * 4);
    int*   bsum   = (int*)alloc(128 * 4);
    float* bufA   = (float*)alloc((size_t)N_NODES * 64 * 4);
    float* bufB   = (float*)alloc((size_t)N_NODES * 64 * 4);
    float* bufC   = (float*)alloc((size_t)N_NODES * 64 * 4);
    if (off > ws_size) return;  // workspace too small; bail (will show as absmax failure)

    const int NB1 = (N_NODES + 1023) / 1024;          // 98
    const int GN  = (N_NODES + 255) / 256;            // 391
    const int GE  = (N_EDGES + 255) / 256;            // 3125
    const int GMM = (N_NODES + 63) / 64;              // 1563 (fc0/conv blocks)
    const int GP  = (N_NODES * 16) / 256;             // 6250 (prop)
    const int GF1 = (N_NODES * 10 + 255) / 256;       // 3907

    // CSR build + degree
    k_zero_cnt<<<GN, 256, 0, stream>>>(cnt);
    k_count<<<GE, 256, 0, stream>>>(col, cnt);
    k_dinv<<<GN, 256, 0, stream>>>(cnt, dinv);
    k_scan1<<<NB1, 256, 0, stream>>>(cnt, starts, bsum);
    k_scan2<<<1, 128, 0, stream>>>(bsum, NB1);
    k_scan3<<<NB1, 256, 0, stream>>>(starts, cursor, bsum);
    k_fill<<<GE, 256, 0, stream>>>(row, col, cursor, csr);

    // fc0
    k_fc0<<<GMM, 256, 0, stream>>>(x, fc0_w, fc0_b, bufA);
    // first conv: h = relu(prop(h)); x0 = h  -> bufC
    k_prop<0><<<GP, 256, 0, stream>>>(bufA, bufC, nullptr, dinv, starts, csr);

    const float betas[4] = {0.f, logf(0.5f / 2.f + 1.f), logf(0.5f / 3.f + 1.f), logf(0.5f / 4.f + 1.f)};

    // layer 1: h currently bufC
    k_prop<1><<<GP, 256, 0, stream>>>(bufC, bufB, bufC, dinv, starts, csr);
    k_conv<<<GMM, 256, 0, stream>>>(bufB, conv_w + 1 * 4096, betas[1], bufA);
    // layers 2..3: h in bufA
    for (int i = 2; i <= 3; ++i) {
        k_prop<1><<<GP, 256, 0, stream>>>(bufA, bufB, bufC, dinv, starts, csr);
        k_conv<<<GMM, 256, 0, stream>>>(bufB, conv_w + (size_t)i * 4096, betas[i], bufA);
    }
    // fc1
    k_fc1<<<GF1, 256, 0, stream>>>(bufA, fc1_w, fc1_b, (float*)d_out);
}

// Round 2
// 441.270 us; speedup vs baseline: 2.9579x; 2.9579x over previous
//
#include <hip/hip_runtime.h>

#define N_NODES 100000
#define N_EDGES 800000
// D_IN=128, D_H=64, N_CLS=40, L=4, ALPHA=0.1, THETA=0.5

__device__ inline float4 f4zero() { return make_float4(0.f, 0.f, 0.f, 0.f); }

__device__ inline float4 fma4(float s, float4 w, float4 a) {
    a.x = fmaf(s, w.x, a.x); a.y = fmaf(s, w.y, a.y);
    a.z = fmaf(s, w.z, a.z); a.w = fmaf(s, w.w, a.w);
    return a;
}

__device__ inline float4 relu4(float4 a) {
    a.x = fmaxf(a.x, 0.f); a.y = fmaxf(a.y, 0.f);
    a.z = fmaxf(a.z, 0.f); a.w = fmaxf(a.w, 0.f);
    return a;
}

__device__ inline float f4c(const float4& v, int i) {
    return reinterpret_cast<const float*>(&v)[i];
}

// ---------------- CSR build ----------------

__global__ __launch_bounds__(256) void k_zero_cnt(int* __restrict__ cnt) {
    int i = blockIdx.x * 256 + threadIdx.x;
    if (i < N_NODES) cnt[i] = 0;
}

__global__ __launch_bounds__(256) void k_count(const int* __restrict__ col, int* __restrict__ cnt) {
    int e = blockIdx.x * 256 + threadIdx.x;
    if (e < N_EDGES) atomicAdd(&cnt[col[e]], 1);
}

__global__ __launch_bounds__(256) void k_dinv(const int* __restrict__ cnt, float* __restrict__ dinv) {
    int i = blockIdx.x * 256 + threadIdx.x;
    if (i < N_NODES) dinv[i] = rsqrtf((float)cnt[i] + 1.0f);  // +1 self loop; deg >= 1 always
}

// block-wise exclusive scan: 1024 items per 256-thread block
__global__ __launch_bounds__(256) void k_scan1(const int* __restrict__ cnt, int* __restrict__ starts,
                                               int* __restrict__ bsum) {
    __shared__ int sh[256];
    int t = threadIdx.x, b = blockIdx.x;
    int base = b * 1024 + t * 4;
    int c0 = 0, c1 = 0, c2 = 0, c3 = 0;
    if (base + 3 < N_NODES) {
        int4 v = *reinterpret_cast<const int4*>(cnt + base);
        c0 = v.x; c1 = v.y; c2 = v.z; c3 = v.w;
    } else {
        if (base + 0 < N_NODES) c0 = cnt[base + 0];
        if (base + 1 < N_NODES) c1 = cnt[base + 1];
        if (base + 2 < N_NODES) c2 = cnt[base + 2];
    }
    int s = c0 + c1 + c2 + c3;
    sh[t] = s;
    __syncthreads();
    for (int off = 1; off < 256; off <<= 1) {
        int add = (t >= off) ? sh[t - off] : 0;
        __syncthreads();
        sh[t] += add;
        __syncthreads();
    }
    int excl = sh[t] - s;
    if (t == 255) bsum[b] = sh[t];
    int p = excl;
    if (base + 0 < N_NODES) starts[base + 0] = p; p += c0;
    if (base + 1 < N_NODES) starts[base + 1] = p; p += c1;
    if (base + 2 < N_NODES) starts[base + 2] = p; p += c2;
    if (base + 3 < N_NODES) starts[base + 3] = p;
}

__global__ __launch_bounds__(128) void k_scan2(int* __restrict__ bsum, int nb) {
    __shared__ int sh[128];
    int t = threadIdx.x;
    int v = (t < nb) ? bsum[t] : 0;
    sh[t] = v;
    __syncthreads();
    for (int off = 1; off < 128; off <<= 1) {
        int add = (t >= off) ? sh[t - off] : 0;
        __syncthreads();
        sh[t] += add;
        __syncthreads();
    }
    if (t < nb) bsum[t] = sh[t] - v;  // exclusive block offsets, in place
}

__global__ __launch_bounds__(256) void k_scan3(int* __restrict__ starts, int* __restrict__ cursor,
                                               const int* __restrict__ bsum) {
    int t = threadIdx.x, b = blockIdx.x;
    int off = bsum[b];
    int base = b * 1024 + t * 4;
#pragma unroll
    for (int j = 0; j < 4; ++j) {
        int i = base + j;
        if (i < N_NODES) {
            int v = starts[i] + off;
            starts[i] = v;
            cursor[i] = v;
        }
    }
    if (b == 0 && t == 0) starts[N_NODES] = N_EDGES;
}

__global__ __launch_bounds__(256) void k_fill(const int* __restrict__ row, const int* __restrict__ col,
                                              int* __restrict__ cursor, int* __restrict__ csr) {
    int e = blockIdx.x * 256 + threadIdx.x;
    if (e < N_EDGES) {
        int c = col[e];
        int p = atomicAdd(&cursor[c], 1);
        csr[p] = row[e];
    }
}

// ---------------- fc0: h = relu(x @ W0 + b0), 128 -> 64 ----------------
// block = 256 threads = 64 nodes; thread: 4 nodes (g) x 4 dims (q, float4)
__global__ __launch_bounds__(256, 4) void k_fc0(const float* __restrict__ x, const float* __restrict__ w,
                                                const float* __restrict__ bias, float* __restrict__ out) {
    __shared__ float4 ws[2048];  // 128 x 16 float4 = 32KB
    const float4* wg = reinterpret_cast<const float4*>(w);
#pragma unroll
    for (int i = 0; i < 8; ++i) ws[threadIdx.x + 256 * i] = wg[threadIdx.x + 256 * i];
    __syncthreads();
    int q = threadIdx.x & 15, g = threadIdx.x >> 4;
    int nbase = blockIdx.x * 64 + g * 4;
    float4 bv = reinterpret_cast<const float4*>(bias)[q];
    float4 a0 = bv, a1 = bv, a2 = bv, a3 = bv;
    const float4* x4 = reinterpret_cast<const float4*>(x);
    bool ok0 = nbase + 0 < N_NODES, ok1 = nbase + 1 < N_NODES;
    bool ok2 = nbase + 2 < N_NODES, ok3 = nbase + 3 < N_NODES;
    // NOTE: unroll capped at 2 — full unroll hoists 128 float4 loads -> 256+ VGPR -> scratch spill
#pragma unroll 2
    for (int kk = 0; kk < 32; ++kk) {
        float4 x0v = ok0 ? x4[(size_t)(nbase + 0) * 32 + kk] : f4zero();
        float4 x1v = ok1 ? x4[(size_t)(nbase + 1) * 32 + kk] : f4zero();
        float4 x2v = ok2 ? x4[(size_t)(nbase + 2) * 32 + kk] : f4zero();
        float4 x3v = ok3 ? x4[(size_t)(nbase + 3) * 32 + kk] : f4zero();
#pragma unroll
        for (int dk = 0; dk < 4; ++dk) {
            float4 w4 = ws[(kk * 4 + dk) * 16 + q];
            a0 = fma4(f4c(x0v, dk), w4, a0);
            a1 = fma4(f4c(x1v, dk), w4, a1);
            a2 = fma4(f4c(x2v, dk), w4, a2);
            a3 = fma4(f4c(x3v, dk), w4, a3);
        }
    }
    float4* o4 = reinterpret_cast<float4*>(out);
    if (ok0) o4[(size_t)(nbase + 0) * 16 + q] = relu4(a0);
    if (ok1) o4[(size_t)(nbase + 1) * 16 + q] = relu4(a1);
    if (ok2) o4[(size_t)(nbase + 2) * 16 + q] = relu4(a2);
    if (ok3) o4[(size_t)(nbase + 3) * 16 + q] = relu4(a3);
}

// ---------------- propagation: out[c] = dinv[c] * (dinv[c]*h[c] + sum dinv[src]*h[src]) ----------------
// MODE 0: out = relu(prop)        (first conv; also becomes x0)
// MODE 1: out = 0.9*prop + 0.1*x0 (alpha combine)
template <int MODE>
__global__ __launch_bounds__(256) void k_prop(const float* __restrict__ hin, float* __restrict__ hout,
                                              const float* __restrict__ x0, const float* __restrict__ dinv,
                                              const int* __restrict__ starts, const int* __restrict__ csr) {
    int t = blockIdx.x * 256 + threadIdx.x;
    int node = t >> 4, q = t & 15;  // 16 lanes per node, float4 per lane
    if (node >= N_NODES) return;
    float dc = dinv[node];
    const float4* h4 = reinterpret_cast<const float4*>(hin);
    float4 hv = h4[(size_t)node * 16 + q];
    float4 acc = make_float4(dc * hv.x, dc * hv.y, dc * hv.z, dc * hv.w);
    int s = starts[node], e = starts[node + 1];
    for (int p = s; p < e; ++p) {
        int src = csr[p];
        float ds = dinv[src];
        float4 v = h4[(size_t)src * 16 + q];
        acc = fma4(ds, v, acc);
    }
    float4 o;
    if (MODE == 0) {
        o = relu4(make_float4(dc * acc.x, dc * acc.y, dc * acc.z, dc * acc.w));
    } else {
        float4 xv = reinterpret_cast<const float4*>(x0)[(size_t)node * 16 + q];
        o.x = fmaf(0.9f * dc, acc.x, 0.1f * xv.x);
        o.y = fmaf(0.9f * dc, acc.y, 0.1f * xv.y);
        o.z = fmaf(0.9f * dc, acc.z, 0.1f * xv.z);
        o.w = fmaf(0.9f * dc, acc.w, 0.1f * xv.w);
    }
    reinterpret_cast<float4*>(hout)[(size_t)node * 16 + q] = o;
}

// ---------------- conv layer: h = relu((1-b)*m + b*(m @ W)), 64x64 ----------------
__global__ __launch_bounds__(256, 4) void k_conv(const float* __restrict__ m, const float* __restrict__ w,
                                                 float beta, float* __restrict__ out) {
    __shared__ float4 ws[1024];  // 64 x 16 float4 = 16KB
    const float4* wg = reinterpret_cast<const float4*>(w);
#pragma unroll
    for (int i = 0; i < 4; ++i) ws[threadIdx.x + 256 * i] = wg[threadIdx.x + 256 * i];
    __syncthreads();
    int q = threadIdx.x & 15, g = threadIdx.x >> 4;
    int nbase = blockIdx.x * 64 + g * 4;
    float4 a0 = f4zero(), a1 = f4zero(), a2 = f4zero(), a3 = f4zero();
    const float4* m4 = reinterpret_cast<const float4*>(m);
    bool ok0 = nbase + 0 < N_NODES, ok1 = nbase + 1 < N_NODES;
    bool ok2 = nbase + 2 < N_NODES, ok3 = nbase + 3 < N_NODES;
    // NOTE: unroll capped at 2 — full unroll hoisted 64 float4 loads -> 256 VGPR -> 750MB scratch traffic
#pragma unroll 2
    for (int kk = 0; kk < 16; ++kk) {
        float4 m0v = ok0 ? m4[(size_t)(nbase + 0) * 16 + kk] : f4zero();
        float4 m1v = ok1 ? m4[(size_t)(nbase + 1) * 16 + kk] : f4zero();
        float4 m2v = ok2 ? m4[(size_t)(nbase + 2) * 16 + kk] : f4zero();
        float4 m3v = ok3 ? m4[(size_t)(nbase + 3) * 16 + kk] : f4zero();
#pragma unroll
        for (int dk = 0; dk < 4; ++dk) {
            float4 w4 = ws[(kk * 4 + dk) * 16 + q];
            a0 = fma4(f4c(m0v, dk), w4, a0);
            a1 = fma4(f4c(m1v, dk), w4, a1);
            a2 = fma4(f4c(m2v, dk), w4, a2);
            a3 = fma4(f4c(m3v, dk), w4, a3);
        }
    }
    float omb = 1.0f - beta;
    float4* o4 = reinterpret_cast<float4*>(out);
    if (ok0) {
        float4 mv = m4[(size_t)(nbase + 0) * 16 + q];
        float4 r = make_float4(fmaf(omb, mv.x, beta * a0.x), fmaf(omb, mv.y, beta * a0.y),
                               fmaf(omb, mv.z, beta * a0.z), fmaf(omb, mv.w, beta * a0.w));
        o4[(size_t)(nbase + 0) * 16 + q] = relu4(r);
    }
    if (ok1) {
        float4 mv = m4[(size_t)(nbase + 1) * 16 + q];
        float4 r = make_float4(fmaf(omb, mv.x, beta * a1.x), fmaf(omb, mv.y, beta * a1.y),
                               fmaf(omb, mv.z, beta * a1.z), fmaf(omb, mv.w, beta * a1.w));
        o4[(size_t)(nbase + 1) * 16 + q] = relu4(r);
    }
    if (ok2) {
        float4 mv = m4[(size_t)(nbase + 2) * 16 + q];
        float4 r = make_float4(fmaf(omb, mv.x, beta * a2.x), fmaf(omb, mv.y, beta * a2.y),
                               fmaf(omb, mv.z, beta * a2.z), fmaf(omb, mv.w, beta * a2.w));
        o4[(size_t)(nbase + 2) * 16 + q] = relu4(r);
    }
    if (ok3) {
        float4 mv = m4[(size_t)(nbase + 3) * 16 + q];
        float4 r = make_float4(fmaf(omb, mv.x, beta * a3.x), fmaf(omb, mv.y, beta * a3.y),
                               fmaf(omb, mv.z, beta * a3.z), fmaf(omb, mv.w, beta * a3.w));
        o4[(size_t)(nbase + 3) * 16 + q] = relu4(r);
    }
}

// ---------------- fc1: out = h @ W1 + b1, 64 -> 40 (no relu) ----------------
__global__ __launch_bounds__(256, 4) void k_fc1(const float* __restrict__ h, const float* __restrict__ w,
                                                const float* __restrict__ bias, float* __restrict__ out) {
    __shared__ float4 ws[640];  // 64 x 10 float4 = 10.24KB
    const float4* wg = reinterpret_cast<const float4*>(w);
    for (int i = threadIdx.x; i < 640; i += 256) ws[i] = wg[i];
    __syncthreads();
    int tg = blockIdx.x * 256 + threadIdx.x;
    int n = tg / 10, q = tg % 10;
    if (n >= N_NODES) return;
    float4 acc = reinterpret_cast<const float4*>(bias)[q];
    const float4* h4 = reinterpret_cast<const float4*>(h);
#pragma unroll 2
    for (int kk = 0; kk < 16; ++kk) {
        float4 hv = h4[(size_t)n * 16 + kk];
#pragma unroll
        for (int dk = 0; dk < 4; ++dk) {
            float4 w4 = ws[(kk * 4 + dk) * 10 + q];
            acc = fma4(f4c(hv, dk), w4, acc);
        }
    }
    reinterpret_cast<float4*>(out)[(size_t)n * 10 + q] = acc;
}

// ---------------- launch ----------------

extern "C" void kernel_launch(void* const* d_in, const int* in_sizes, int n_in,
                              void* d_out, int out_size, void* d_ws, size_t ws_size,
                              hipStream_t stream) {
    const float* x      = (const float*)d_in[0];
    const int*   ei     = (const int*)d_in[1];
    const float* fc0_w  = (const float*)d_in[2];
    const float* fc0_b  = (const float*)d_in[3];
    const float* fc1_w  = (const float*)d_in[4];
    const float* fc1_b  = (const float*)d_in[5];
    const float* conv_w = (const float*)d_in[6];
    const int* row = ei;
    const int* col = ei + N_EDGES;

    char* ws = (char*)d_ws;
    size_t off = 0;
    auto alloc = [&](size_t bytes) -> void* {
        void* p = ws + off;
        off += (bytes + 255) & ~(size_t)255;
        return p;
    };
    float* dinv   = (float*)alloc((size_t)N_NODES * 4);
    int*   cnt    = (int*)alloc((size_t)N_NODES * 4);
    int*   starts = (int*)alloc((size_t)(N_NODES + 1) * 4);
    int*   cursor = (int*)alloc((size_t)(N_NODES + 1) * 4);
    int*   csr    = (int*)alloc((size_t)N_EDGES * 4);
    int*   bsum   = (int*)alloc(128 * 4);
    float* bufA   = (float*)alloc((size_t)N_NODES * 64 * 4);
    float* bufB   = (float*)alloc((size_t)N_NODES * 64 * 4);
    float* bufC   = (float*)alloc((size_t)N_NODES * 64 * 4);
    if (off > ws_size) return;  // workspace too small; bail (will show as absmax failure)

    const int NB1 = (N_NODES + 1023) / 1024;          // 98
    const int GN  = (N_NODES + 255) / 256;            // 391
    const int GE  = (N_EDGES + 255) / 256;            // 3125
    const int GMM = (N_NODES + 63) / 64;              // 1563 (fc0/conv blocks)
    const int GP  = (N_NODES * 16) / 256;             // 6250 (prop)
    const int GF1 = (N_NODES * 10 + 255) / 256;       // 3907

    // CSR build + degree
    k_zero_cnt<<<GN, 256, 0, stream>>>(cnt);
    k_count<<<GE, 256, 0, stream>>>(col, cnt);
    k_dinv<<<GN, 256, 0, stream>>>(cnt, dinv);
    k_scan1<<<NB1, 256, 0, stream>>>(cnt, starts, bsum);
    k_scan2<<<1, 128, 0, stream>>>(bsum, NB1);
    k_scan3<<<NB1, 256, 0, stream>>>(starts, cursor, bsum);
    k_fill<<<GE, 256, 0, stream>>>(row, col, cursor, csr);

    // fc0
    k_fc0<<<GMM, 256, 0, stream>>>(x, fc0_w, fc0_b, bufA);
    // first conv: h = relu(prop(h)); x0 = h  -> bufC
    k_prop<0><<<GP, 256, 0, stream>>>(bufA, bufC, nullptr, dinv, starts, csr);

    const float betas[4] = {0.f, logf(0.5f / 2.f + 1.f), logf(0.5f / 3.f + 1.f), logf(0.5f / 4.f + 1.f)};

    // layer 1: h currently bufC
    k_prop<1><<<GP, 256, 0, stream>>>(bufC, bufB, bufC, dinv, starts, csr);
    k_conv<<<GMM, 256, 0, stream>>>(bufB, conv_w + 1 * 4096, betas[1], bufA);
    // layers 2..3: h in bufA
    for (int i = 2; i <= 3; ++i) {
        k_prop<1><<<GP, 256, 0, stream>>>(bufA, bufB, bufC, dinv, starts, csr);
        k_conv<<<GMM, 256, 0, stream>>>(bufB, conv_w + (size_t)i * 4096, betas[i], bufA);
    }
    // fc1
    k_fc1<<<GF1, 256, 0, stream>>>(bufA, fc1_w, fc1_b, (float*)d_out);
}

// Round 3
// 347.313 us; speedup vs baseline: 3.7581x; 1.2705x over previous
//
#include <hip/hip_runtime.h>

#define N_NODES 100000
#define N_EDGES 800000
// D_IN=128, D_H=64, N_CLS=40, L=4, ALPHA=0.1, THETA=0.5

__device__ inline float4 f4zero() { return make_float4(0.f, 0.f, 0.f, 0.f); }

__device__ inline float4 fma4(float s, float4 w, float4 a) {
    a.x = fmaf(s, w.x, a.x); a.y = fmaf(s, w.y, a.y);
    a.z = fmaf(s, w.z, a.z); a.w = fmaf(s, w.w, a.w);
    return a;
}

__device__ inline float4 relu4(float4 a) {
    a.x = fmaxf(a.x, 0.f); a.y = fmaxf(a.y, 0.f);
    a.z = fmaxf(a.z, 0.f); a.w = fmaxf(a.w, 0.f);
    return a;
}

__device__ inline float f4c(const float4& v, int i) {
    return reinterpret_cast<const float*>(&v)[i];
}

// ---------------- CSR build ----------------

__global__ __launch_bounds__(256) void k_zero_cnt(int* __restrict__ cnt) {
    int i = blockIdx.x * 256 + threadIdx.x;
    if (i < N_NODES) cnt[i] = 0;
}

__global__ __launch_bounds__(256) void k_count(const int* __restrict__ col, int* __restrict__ cnt) {
    int e = blockIdx.x * 256 + threadIdx.x;
    if (e < N_EDGES) atomicAdd(&cnt[col[e]], 1);
}

__global__ __launch_bounds__(256) void k_dinv(const int* __restrict__ cnt, float* __restrict__ dinv) {
    int i = blockIdx.x * 256 + threadIdx.x;
    if (i < N_NODES) dinv[i] = rsqrtf((float)cnt[i] + 1.0f);  // +1 self loop; deg >= 1 always
}

// block-wise exclusive scan: 1024 items per 256-thread block
__global__ __launch_bounds__(256) void k_scan1(const int* __restrict__ cnt, int* __restrict__ starts,
                                               int* __restrict__ bsum) {
    __shared__ int sh[256];
    int t = threadIdx.x, b = blockIdx.x;
    int base = b * 1024 + t * 4;
    int c0 = 0, c1 = 0, c2 = 0, c3 = 0;
    if (base + 3 < N_NODES) {
        int4 v = *reinterpret_cast<const int4*>(cnt + base);
        c0 = v.x; c1 = v.y; c2 = v.z; c3 = v.w;
    } else {
        if (base + 0 < N_NODES) c0 = cnt[base + 0];
        if (base + 1 < N_NODES) c1 = cnt[base + 1];
        if (base + 2 < N_NODES) c2 = cnt[base + 2];
    }
    int s = c0 + c1 + c2 + c3;
    sh[t] = s;
    __syncthreads();
    for (int off = 1; off < 256; off <<= 1) {
        int add = (t >= off) ? sh[t - off] : 0;
        __syncthreads();
        sh[t] += add;
        __syncthreads();
    }
    int excl = sh[t] - s;
    if (t == 255) bsum[b] = sh[t];
    int p = excl;
    if (base + 0 < N_NODES) starts[base + 0] = p; p += c0;
    if (base + 1 < N_NODES) starts[base + 1] = p; p += c1;
    if (base + 2 < N_NODES) starts[base + 2] = p; p += c2;
    if (base + 3 < N_NODES) starts[base + 3] = p;
}

__global__ __launch_bounds__(128) void k_scan2(int* __restrict__ bsum, int nb) {
    __shared__ int sh[128];
    int t = threadIdx.x;
    int v = (t < nb) ? bsum[t] : 0;
    sh[t] = v;
    __syncthreads();
    for (int off = 1; off < 128; off <<= 1) {
        int add = (t >= off) ? sh[t - off] : 0;
        __syncthreads();
        sh[t] += add;
        __syncthreads();
    }
    if (t < nb) bsum[t] = sh[t] - v;  // exclusive block offsets, in place
}

__global__ __launch_bounds__(256) void k_scan3(int* __restrict__ starts, int* __restrict__ cursor,
                                               const int* __restrict__ bsum) {
    int t = threadIdx.x, b = blockIdx.x;
    int off = bsum[b];
    int base = b * 1024 + t * 4;
#pragma unroll
    for (int j = 0; j < 4; ++j) {
        int i = base + j;
        if (i < N_NODES) {
            int v = starts[i] + off;
            starts[i] = v;
            cursor[i] = v;
        }
    }
    if (b == 0 && t == 0) starts[N_NODES] = N_EDGES;
}

// fused CSR entry: {src, dinv[src]} — removes the dependent dinv load from the prop hot loop
__global__ __launch_bounds__(256) void k_fill(const int* __restrict__ row, const int* __restrict__ col,
                                              const float* __restrict__ dinv,
                                              int* __restrict__ cursor, int2* __restrict__ csr2) {
    int e = blockIdx.x * 256 + threadIdx.x;
    if (e < N_EDGES) {
        int c = col[e];
        int r = row[e];
        float ds = dinv[r];
        int p = atomicAdd(&cursor[c], 1);
        csr2[p] = make_int2(r, __float_as_int(ds));
    }
}

// ---------------- fc0: h = relu(x @ W0 + b0), 128 -> 64 ----------------
// 256 threads = 64 nodes; x tile + W staged in LDS (65KB -> 2 blocks/CU)
__global__ __launch_bounds__(256, 2) void k_fc0(const float* __restrict__ x, const float* __restrict__ w,
                                                const float* __restrict__ bias, float* __restrict__ out) {
    __shared__ float4 ws[2048];     // W: 128 rows x 16 float4 = 32KB
    __shared__ float4 xs[64 * 33];  // x tile: 64 rows x 32 float4, pad->33 (2-way bank alias = free)
    const float4* wg = reinterpret_cast<const float4*>(w);
    const float4* x4 = reinterpret_cast<const float4*>(x);
    int tid = threadIdx.x;
    int base = blockIdx.x * 64;
#pragma unroll
    for (int i = 0; i < 8; ++i) ws[tid + 256 * i] = wg[tid + 256 * i];
#pragma unroll
    for (int j = 0; j < 8; ++j) {
        int f = tid + 256 * j;           // 0..2047
        int ln = f >> 5, c = f & 31;
        xs[ln * 33 + c] = (base + ln < N_NODES) ? x4[(size_t)(base + ln) * 32 + c] : f4zero();
    }
    __syncthreads();
    int q = tid & 15, lbase = (tid >> 4) * 4;
    float4 bv = reinterpret_cast<const float4*>(bias)[q];
    float4 a0 = bv, a1 = bv, a2 = bv, a3 = bv;
#pragma unroll 4
    for (int kk = 0; kk < 32; ++kk) {
        float4 x0v = xs[(lbase + 0) * 33 + kk];
        float4 x1v = xs[(lbase + 1) * 33 + kk];
        float4 x2v = xs[(lbase + 2) * 33 + kk];
        float4 x3v = xs[(lbase + 3) * 33 + kk];
#pragma unroll
        for (int dk = 0; dk < 4; ++dk) {
            float4 w4 = ws[(kk * 4 + dk) * 16 + q];
            a0 = fma4(f4c(x0v, dk), w4, a0);
            a1 = fma4(f4c(x1v, dk), w4, a1);
            a2 = fma4(f4c(x2v, dk), w4, a2);
            a3 = fma4(f4c(x3v, dk), w4, a3);
        }
    }
    float4* o4 = reinterpret_cast<float4*>(out);
    int n = base + lbase;
    if (n + 0 < N_NODES) o4[(size_t)(n + 0) * 16 + q] = relu4(a0);
    if (n + 1 < N_NODES) o4[(size_t)(n + 1) * 16 + q] = relu4(a1);
    if (n + 2 < N_NODES) o4[(size_t)(n + 2) * 16 + q] = relu4(a2);
    if (n + 3 < N_NODES) o4[(size_t)(n + 3) * 16 + q] = relu4(a3);
}

// ---------------- propagation ----------------
// out[c] = f( dinv[c] * (dinv[c]*h[c] + sum_src dinv[src]*h[src]) )
// MODE 0: relu(.)  (first conv; becomes x0)   MODE 1: 0.9*(.) + 0.1*x0
// 4-wide software-pipelined gather loop over fused int2 CSR.
template <int MODE>
__global__ __launch_bounds__(256) void k_prop(const float* __restrict__ hin, float* __restrict__ hout,
                                              const float* __restrict__ x0, const float* __restrict__ dinv,
                                              const int* __restrict__ starts, const int2* __restrict__ csr2) {
    int t = blockIdx.x * 256 + threadIdx.x;
    int node = t >> 4, q = t & 15;  // 16 lanes per node, float4 per lane
    if (node >= N_NODES) return;
    float dc = dinv[node];
    const float4* h4 = reinterpret_cast<const float4*>(hin);
    float4 hv = h4[(size_t)node * 16 + q];
    float4 acc = make_float4(dc * hv.x, dc * hv.y, dc * hv.z, dc * hv.w);
    int s = starts[node], e = starts[node + 1];
    int l = e - 1;
    for (int p = s; p < e; p += 4) {
        int2 e0 = csr2[p];
        int2 e1 = csr2[min(p + 1, l)];
        int2 e2 = csr2[min(p + 2, l)];
        int2 e3 = csr2[min(p + 3, l)];
        float4 v0 = h4[(size_t)(e0.x) * 16 + q];
        float4 v1 = h4[(size_t)(e1.x) * 16 + q];
        float4 v2 = h4[(size_t)(e2.x) * 16 + q];
        float4 v3 = h4[(size_t)(e3.x) * 16 + q];
        float w0 = __int_as_float(e0.y);
        float w1 = (p + 1 < e) ? __int_as_float(e1.y) : 0.f;
        float w2 = (p + 2 < e) ? __int_as_float(e2.y) : 0.f;
        float w3 = (p + 3 < e) ? __int_as_float(e3.y) : 0.f;
        acc = fma4(w0, v0, acc);
        acc = fma4(w1, v1, acc);
        acc = fma4(w2, v2, acc);
        acc = fma4(w3, v3, acc);
    }
    float4 o;
    if (MODE == 0) {
        o = relu4(make_float4(dc * acc.x, dc * acc.y, dc * acc.z, dc * acc.w));
    } else {
        float4 xv = reinterpret_cast<const float4*>(x0)[(size_t)node * 16 + q];
        o.x = fmaf(0.9f * dc, acc.x, 0.1f * xv.x);
        o.y = fmaf(0.9f * dc, acc.y, 0.1f * xv.y);
        o.z = fmaf(0.9f * dc, acc.z, 0.1f * xv.z);
        o.w = fmaf(0.9f * dc, acc.w, 0.1f * xv.w);
    }
    reinterpret_cast<float4*>(hout)[(size_t)node * 16 + q] = o;
}

// ---------------- conv layer: h = relu((1-b)*m + b*(m @ W)), 64x64 ----------------
// m tile staged in LDS (pad 17 -> 2-way alias, free); epilogue re-read is LDS-local.
__global__ __launch_bounds__(256, 4) void k_conv(const float* __restrict__ m, const float* __restrict__ w,
                                                 float beta, float* __restrict__ out) {
    __shared__ float4 ws[1024];     // 64 x 16 float4 = 16KB
    __shared__ float4 ms[64 * 17];  // 64 x 16 float4, pad->17
    const float4* wg = reinterpret_cast<const float4*>(w);
    const float4* m4 = reinterpret_cast<const float4*>(m);
    int tid = threadIdx.x;
    int base = blockIdx.x * 64;
#pragma unroll
    for (int i = 0; i < 4; ++i) ws[tid + 256 * i] = wg[tid + 256 * i];
#pragma unroll
    for (int j = 0; j < 4; ++j) {
        int f = tid + 256 * j;          // 0..1023
        int ln = f >> 4, c = f & 15;
        ms[ln * 17 + c] = (base + ln < N_NODES) ? m4[(size_t)(base + ln) * 16 + c] : f4zero();
    }
    __syncthreads();
    int q = tid & 15, lbase = (tid >> 4) * 4;
    float4 a0 = f4zero(), a1 = f4zero(), a2 = f4zero(), a3 = f4zero();
#pragma unroll 4
    for (int kk = 0; kk < 16; ++kk) {
        float4 m0v = ms[(lbase + 0) * 17 + kk];
        float4 m1v = ms[(lbase + 1) * 17 + kk];
        float4 m2v = ms[(lbase + 2) * 17 + kk];
        float4 m3v = ms[(lbase + 3) * 17 + kk];
#pragma unroll
        for (int dk = 0; dk < 4; ++dk) {
            float4 w4 = ws[(kk * 4 + dk) * 16 + q];
            a0 = fma4(f4c(m0v, dk), w4, a0);
            a1 = fma4(f4c(m1v, dk), w4, a1);
            a2 = fma4(f4c(m2v, dk), w4, a2);
            a3 = fma4(f4c(m3v, dk), w4, a3);
        }
    }
    float omb = 1.0f - beta;
    float4* o4 = reinterpret_cast<float4*>(out);
#pragma unroll
    for (int i = 0; i < 4; ++i) {
        int n = base + lbase + i;
        if (n < N_NODES) {
            float4 acc = (i == 0) ? a0 : (i == 1) ? a1 : (i == 2) ? a2 : a3;
            float4 mv = ms[(lbase + i) * 17 + q];
            float4 r = make_float4(fmaf(omb, mv.x, beta * acc.x), fmaf(omb, mv.y, beta * acc.y),
                                   fmaf(omb, mv.z, beta * acc.z), fmaf(omb, mv.w, beta * acc.w));
            o4[(size_t)n * 16 + q] = relu4(r);
        }
    }
}

// ---------------- fc1: out = h @ W1 + b1, 64 -> 40 (no relu) ----------------
// 320 threads = 32 nodes x 10 q; h tile staged in LDS.
__global__ __launch_bounds__(320, 2) void k_fc1(const float* __restrict__ h, const float* __restrict__ w,
                                                const float* __restrict__ bias, float* __restrict__ out) {
    __shared__ float4 ws[640];      // 64 x 10 float4 = 10.24KB
    __shared__ float4 hs[32 * 17];  // 32 x 16 float4, pad->17
    const float4* wg = reinterpret_cast<const float4*>(w);
    const float4* h4 = reinterpret_cast<const float4*>(h);
    int tid = threadIdx.x;
    int base = blockIdx.x * 32;
    for (int i = tid; i < 640; i += 320) ws[i] = wg[i];
    for (int i = tid; i < 512; i += 320) {
        int ln = i >> 4, c = i & 15;
        hs[ln * 17 + c] = (base + ln < N_NODES) ? h4[(size_t)(base + ln) * 16 + c] : f4zero();
    }
    __syncthreads();
    int ln = tid / 10, q = tid - ln * 10;  // tid<320 -> ln<32
    int n = base + ln;
    float4 acc = reinterpret_cast<const float4*>(bias)[q];
#pragma unroll 4
    for (int kk = 0; kk < 16; ++kk) {
        float4 hv = hs[ln * 17 + kk];
#pragma unroll
        for (int dk = 0; dk < 4; ++dk) {
            acc = fma4(f4c(hv, dk), ws[(kk * 4 + dk) * 10 + q], acc);
        }
    }
    if (n < N_NODES) reinterpret_cast<float4*>(out)[(size_t)n * 10 + q] = acc;
}

// ---------------- launch ----------------

extern "C" void kernel_launch(void* const* d_in, const int* in_sizes, int n_in,
                              void* d_out, int out_size, void* d_ws, size_t ws_size,
                              hipStream_t stream) {
    const float* x      = (const float*)d_in[0];
    const int*   ei     = (const int*)d_in[1];
    const float* fc0_w  = (const float*)d_in[2];
    const float* fc0_b  = (const float*)d_in[3];
    const float* fc1_w  = (const float*)d_in[4];
    const float* fc1_b  = (const float*)d_in[5];
    const float* conv_w = (const float*)d_in[6];
    const int* row = ei;
    const int* col = ei + N_EDGES;

    char* ws = (char*)d_ws;
    size_t off = 0;
    auto alloc = [&](size_t bytes) -> void* {
        void* p = ws + off;
        off += (bytes + 255) & ~(size_t)255;
        return p;
    };
    float* dinv   = (float*)alloc((size_t)N_NODES * 4);
    int*   cnt    = (int*)alloc((size_t)N_NODES * 4);
    int*   starts = (int*)alloc((size_t)(N_NODES + 1) * 4);
    int*   cursor = (int*)alloc((size_t)(N_NODES + 1) * 4);
    int2*  csr2   = (int2*)alloc((size_t)N_EDGES * 8);
    int*   bsum   = (int*)alloc(128 * 4);
    float* bufA   = (float*)alloc((size_t)N_NODES * 64 * 4);
    float* bufB   = (float*)alloc((size_t)N_NODES * 64 * 4);
    float* bufC   = (float*)alloc((size_t)N_NODES * 64 * 4);
    if (off > ws_size) return;  // workspace too small; bail (will show as absmax failure)

    const int NB1 = (N_NODES + 1023) / 1024;          // 98
    const int GN  = (N_NODES + 255) / 256;            // 391
    const int GE  = (N_EDGES + 255) / 256;            // 3125
    const int GMM = (N_NODES + 63) / 64;              // 1563 (fc0/conv blocks)
    const int GP  = (N_NODES * 16) / 256;             // 6250 (prop)
    const int GF1 = (N_NODES + 31) / 32;              // 3125 (fc1 blocks, 320 thr)

    // CSR build + degree
    k_zero_cnt<<<GN, 256, 0, stream>>>(cnt);
    k_count<<<GE, 256, 0, stream>>>(col, cnt);
    k_dinv<<<GN, 256, 0, stream>>>(cnt, dinv);
    k_scan1<<<NB1, 256, 0, stream>>>(cnt, starts, bsum);
    k_scan2<<<1, 128, 0, stream>>>(bsum, NB1);
    k_scan3<<<NB1, 256, 0, stream>>>(starts, cursor, bsum);
    k_fill<<<GE, 256, 0, stream>>>(row, col, dinv, cursor, csr2);

    // fc0
    k_fc0<<<GMM, 256, 0, stream>>>(x, fc0_w, fc0_b, bufA);
    // first conv: h = relu(prop(h)); x0 = h  -> bufC
    k_prop<0><<<GP, 256, 0, stream>>>(bufA, bufC, nullptr, dinv, starts, csr2);

    const float betas[4] = {0.f, logf(0.5f / 2.f + 1.f), logf(0.5f / 3.f + 1.f), logf(0.5f / 4.f + 1.f)};

    // layer 1: h currently bufC
    k_prop<1><<<GP, 256, 0, stream>>>(bufC, bufB, bufC, dinv, starts, csr2);
    k_conv<<<GMM, 256, 0, stream>>>(bufB, conv_w + 1 * 4096, betas[1], bufA);
    // layers 2..3: h in bufA
    for (int i = 2; i <= 3; ++i) {
        k_prop<1><<<GP, 256, 0, stream>>>(bufA, bufB, bufC, dinv, starts, csr2);
        k_conv<<<GMM, 256, 0, stream>>>(bufB, conv_w + (size_t)i * 4096, betas[i], bufA);
    }
    // fc1
    k_fc1<<<GF1, 320, 0, stream>>>(bufA, fc1_w, fc1_b, (float*)d_out);
}

// Round 4
// 298.070 us; speedup vs baseline: 4.3790x; 1.1652x over previous
//
#include <hip/hip_runtime.h>

#define N_NODES 100000
#define N_EDGES 800000
// D_IN=128, D_H=64, N_CLS=40, L=4, ALPHA=0.1, THETA=0.5
// NOTE: N_NODES % 16 == 0 (6250 blocks of 16 nodes exactly) — no bounds checks in propconv.

__device__ inline float4 f4zero() { return make_float4(0.f, 0.f, 0.f, 0.f); }

__device__ inline float4 fma4(float s, float4 w, float4 a) {
    a.x = fmaf(s, w.x, a.x); a.y = fmaf(s, w.y, a.y);
    a.z = fmaf(s, w.z, a.z); a.w = fmaf(s, w.w, a.w);
    return a;
}

__device__ inline float4 relu4(float4 a) {
    a.x = fmaxf(a.x, 0.f); a.y = fmaxf(a.y, 0.f);
    a.z = fmaxf(a.z, 0.f); a.w = fmaxf(a.w, 0.f);
    return a;
}

__device__ inline float f4c(const float4& v, int i) {
    return reinterpret_cast<const float*>(&v)[i];
}

// ---------------- CSR build ----------------

__global__ __launch_bounds__(256) void k_zero_cnt(int* __restrict__ cnt) {
    int i = blockIdx.x * 256 + threadIdx.x;
    if (i < N_NODES) cnt[i] = 0;
}

__global__ __launch_bounds__(256) void k_count(const int* __restrict__ col, int* __restrict__ cnt) {
    int e = blockIdx.x * 256 + threadIdx.x;
    if (e < N_EDGES) atomicAdd(&cnt[col[e]], 1);
}

// block-wise exclusive scan: 1024 items per 256-thread block; also emits dinv (fused old k_dinv)
__global__ __launch_bounds__(256) void k_scan1(const int* __restrict__ cnt, int* __restrict__ starts,
                                               int* __restrict__ bsum, float* __restrict__ dinv) {
    __shared__ int sh[256];
    int t = threadIdx.x, b = blockIdx.x;
    int base = b * 1024 + t * 4;
    int c0 = 0, c1 = 0, c2 = 0, c3 = 0;
    if (base + 3 < N_NODES) {
        int4 v = *reinterpret_cast<const int4*>(cnt + base);
        c0 = v.x; c1 = v.y; c2 = v.z; c3 = v.w;
    } else {
        if (base + 0 < N_NODES) c0 = cnt[base + 0];
        if (base + 1 < N_NODES) c1 = cnt[base + 1];
        if (base + 2 < N_NODES) c2 = cnt[base + 2];
    }
    if (base + 0 < N_NODES) dinv[base + 0] = rsqrtf((float)c0 + 1.0f);
    if (base + 1 < N_NODES) dinv[base + 1] = rsqrtf((float)c1 + 1.0f);
    if (base + 2 < N_NODES) dinv[base + 2] = rsqrtf((float)c2 + 1.0f);
    if (base + 3 < N_NODES) dinv[base + 3] = rsqrtf((float)c3 + 1.0f);
    int s = c0 + c1 + c2 + c3;
    sh[t] = s;
    __syncthreads();
    for (int off = 1; off < 256; off <<= 1) {
        int add = (t >= off) ? sh[t - off] : 0;
        __syncthreads();
        sh[t] += add;
        __syncthreads();
    }
    int excl = sh[t] - s;
    if (t == 255) bsum[b] = sh[t];
    int p = excl;
    if (base + 0 < N_NODES) starts[base + 0] = p; p += c0;
    if (base + 1 < N_NODES) starts[base + 1] = p; p += c1;
    if (base + 2 < N_NODES) starts[base + 2] = p; p += c2;
    if (base + 3 < N_NODES) starts[base + 3] = p;
}

__global__ __launch_bounds__(128) void k_scan2(int* __restrict__ bsum, int nb) {
    __shared__ int sh[128];
    int t = threadIdx.x;
    int v = (t < nb) ? bsum[t] : 0;
    sh[t] = v;
    __syncthreads();
    for (int off = 1; off < 128; off <<= 1) {
        int add = (t >= off) ? sh[t - off] : 0;
        __syncthreads();
        sh[t] += add;
        __syncthreads();
    }
    if (t < nb) bsum[t] = sh[t] - v;  // exclusive block offsets, in place
}

__global__ __launch_bounds__(256) void k_scan3(int* __restrict__ starts, int* __restrict__ cursor,
                                               const int* __restrict__ bsum) {
    int t = threadIdx.x, b = blockIdx.x;
    int off = bsum[b];
    int base = b * 1024 + t * 4;
#pragma unroll
    for (int j = 0; j < 4; ++j) {
        int i = base + j;
        if (i < N_NODES) {
            int v = starts[i] + off;
            starts[i] = v;
            cursor[i] = v;
        }
    }
    if (b == 0 && t == 0) starts[N_NODES] = N_EDGES;
}

// fused CSR entry: {src, dinv[src]}
__global__ __launch_bounds__(256) void k_fill(const int* __restrict__ row, const int* __restrict__ col,
                                              const float* __restrict__ dinv,
                                              int* __restrict__ cursor, int2* __restrict__ csr2) {
    int e = blockIdx.x * 256 + threadIdx.x;
    if (e < N_EDGES) {
        int c = col[e];
        int r = row[e];
        float ds = dinv[r];
        int p = atomicAdd(&cursor[c], 1);
        csr2[p] = make_int2(r, __float_as_int(ds));
    }
}

// ---------------- fc0: h = relu(x @ W0 + b0), 128 -> 64 ----------------
__global__ __launch_bounds__(256, 2) void k_fc0(const float* __restrict__ x, const float* __restrict__ w,
                                                const float* __restrict__ bias, float* __restrict__ out) {
    __shared__ float4 ws[2048];     // W: 128 rows x 16 float4 = 32KB
    __shared__ float4 xs[64 * 33];  // x tile: 64 rows x 32 float4, pad->33
    const float4* wg = reinterpret_cast<const float4*>(w);
    const float4* x4 = reinterpret_cast<const float4*>(x);
    int tid = threadIdx.x;
    int base = blockIdx.x * 64;
#pragma unroll
    for (int i = 0; i < 8; ++i) ws[tid + 256 * i] = wg[tid + 256 * i];
#pragma unroll
    for (int j = 0; j < 8; ++j) {
        int f = tid + 256 * j;
        int ln = f >> 5, c = f & 31;
        xs[ln * 33 + c] = (base + ln < N_NODES) ? x4[(size_t)(base + ln) * 32 + c] : f4zero();
    }
    __syncthreads();
    int q = tid & 15, lbase = (tid >> 4) * 4;
    float4 bv = reinterpret_cast<const float4*>(bias)[q];
    float4 a0 = bv, a1 = bv, a2 = bv, a3 = bv;
#pragma unroll 4
    for (int kk = 0; kk < 32; ++kk) {
        float4 x0v = xs[(lbase + 0) * 33 + kk];
        float4 x1v = xs[(lbase + 1) * 33 + kk];
        float4 x2v = xs[(lbase + 2) * 33 + kk];
        float4 x3v = xs[(lbase + 3) * 33 + kk];
#pragma unroll
        for (int dk = 0; dk < 4; ++dk) {
            float4 w4 = ws[(kk * 4 + dk) * 16 + q];
            a0 = fma4(f4c(x0v, dk), w4, a0);
            a1 = fma4(f4c(x1v, dk), w4, a1);
            a2 = fma4(f4c(x2v, dk), w4, a2);
            a3 = fma4(f4c(x3v, dk), w4, a3);
        }
    }
    float4* o4 = reinterpret_cast<float4*>(out);
    int n = base + lbase;
    if (n + 0 < N_NODES) o4[(size_t)(n + 0) * 16 + q] = relu4(a0);
    if (n + 1 < N_NODES) o4[(size_t)(n + 1) * 16 + q] = relu4(a1);
    if (n + 2 < N_NODES) o4[(size_t)(n + 2) * 16 + q] = relu4(a2);
    if (n + 3 < N_NODES) o4[(size_t)(n + 3) * 16 + q] = relu4(a3);
}

// ---------------- 8-wide gather core ----------------
__device__ __forceinline__ float4 prop_gather(const float4* __restrict__ h4, int q,
                                              float4 hv_self, float dc,
                                              int s, int e, const int2* __restrict__ csr2) {
    float4 acc = make_float4(dc * hv_self.x, dc * hv_self.y, dc * hv_self.z, dc * hv_self.w);
    int l = e - 1;
    for (int p = s; p < e; p += 8) {
        float4 vv[8];
        float ww[8];
#pragma unroll
        for (int j = 0; j < 8; ++j) {
            int idx = min(p + j, l);
            int2 ee = csr2[idx];
            vv[j] = h4[(size_t)(ee.x) * 16 + q];
            ww[j] = (p + j <= l) ? __int_as_float(ee.y) : 0.f;
        }
#pragma unroll
        for (int j = 0; j < 8; ++j) acc = fma4(ww[j], vv[j], acc);
    }
    return acc;
}

// ---------------- prop0: h = relu(prop(h)) (first conv; becomes x0) ----------------
__global__ __launch_bounds__(256) void k_prop0(const float* __restrict__ hin, float* __restrict__ hout,
                                               const float* __restrict__ dinv,
                                               const int* __restrict__ starts, const int2* __restrict__ csr2) {
    int t = blockIdx.x * 256 + threadIdx.x;
    int node = t >> 4, q = t & 15;
    float dc = dinv[node];
    const float4* h4 = reinterpret_cast<const float4*>(hin);
    float4 hv = h4[(size_t)node * 16 + q];
    float4 acc = prop_gather(h4, q, hv, dc, starts[node], starts[node + 1], csr2);
    float4 o = relu4(make_float4(dc * acc.x, dc * acc.y, dc * acc.z, dc * acc.w));
    reinterpret_cast<float4*>(hout)[(size_t)node * 16 + q] = o;
}

// ---------------- fused: prop + alpha-combine + conv [+ fc1] ----------------
// block = 256 threads = 16 nodes (nl = tid>>4, q = tid&15, float4 per lane)
// m = 0.9*dc*gather + 0.1*x0 ; h = relu((1-b)*m + b*(m @ W))
// FINAL: additionally out = h @ W1 + b1 -> d_out (40 floats/node)
template <bool FINAL>
__global__ __launch_bounds__(256, 4) void k_propconv(const float* __restrict__ hin,
                                                     const float* __restrict__ x0,
                                                     const float* __restrict__ dinv,
                                                     const int* __restrict__ starts,
                                                     const int2* __restrict__ csr2,
                                                     const float* __restrict__ w, float beta,
                                                     const float* __restrict__ w1,
                                                     const float* __restrict__ b1,
                                                     float* __restrict__ out) {
    __shared__ float4 ws[1024];                  // conv W: 64 x 16 float4 = 16KB
    __shared__ float4 ms[16 * 17];               // m tile, pad->17
    __shared__ float4 hs[FINAL ? 16 * 17 : 1];   // conv output tile (FINAL only)
    __shared__ float4 ws1[FINAL ? 640 : 1];      // fc1 W (FINAL only)

    int tid = threadIdx.x;
    int nl = tid >> 4, q = tid & 15;
    int node = blockIdx.x * 16 + nl;

    // stage weights early; loads complete under the gather phase
    const float4* wg = reinterpret_cast<const float4*>(w);
#pragma unroll
    for (int i = 0; i < 4; ++i) ws[tid + 256 * i] = wg[tid + 256 * i];
    if constexpr (FINAL) {
        const float4* w1g = reinterpret_cast<const float4*>(w1);
        for (int i = tid; i < 640; i += 256) ws1[i] = w1g[i];
    }

    // prop + alpha combine
    float dc = dinv[node];
    const float4* h4 = reinterpret_cast<const float4*>(hin);
    float4 hv = h4[(size_t)node * 16 + q];
    float4 acc = prop_gather(h4, q, hv, dc, starts[node], starts[node + 1], csr2);
    float4 xv = reinterpret_cast<const float4*>(x0)[(size_t)node * 16 + q];
    float4 m;
    m.x = fmaf(0.9f * dc, acc.x, 0.1f * xv.x);
    m.y = fmaf(0.9f * dc, acc.y, 0.1f * xv.y);
    m.z = fmaf(0.9f * dc, acc.z, 0.1f * xv.z);
    m.w = fmaf(0.9f * dc, acc.w, 0.1f * xv.w);
    ms[nl * 17 + q] = m;
    __syncthreads();

    // conv from LDS: a = m_row @ W  (thread computes cols 4q..4q+3 of node nl)
    float4 a = f4zero();
#pragma unroll 4
    for (int kk = 0; kk < 16; ++kk) {
        float4 mv = ms[nl * 17 + kk];  // broadcast within 16-lane group
#pragma unroll
        for (int dk = 0; dk < 4; ++dk) {
            a = fma4(f4c(mv, dk), ws[(kk * 4 + dk) * 16 + q], a);
        }
    }
    float omb = 1.0f - beta;
    float4 r = make_float4(fmaf(omb, m.x, beta * a.x), fmaf(omb, m.y, beta * a.y),
                           fmaf(omb, m.z, beta * a.z), fmaf(omb, m.w, beta * a.w));
    r = relu4(r);

    if constexpr (!FINAL) {
        reinterpret_cast<float4*>(out)[(size_t)node * 16 + q] = r;
    } else {
        hs[nl * 17 + q] = r;
        __syncthreads();
        // fc1: 160 active threads = 16 nodes x 10 q4 outputs
        if (tid < 160) {
            int ln = tid / 10, qq = tid - ln * 10;
            float4 acc1 = reinterpret_cast<const float4*>(b1)[qq];
#pragma unroll 4
            for (int kk = 0; kk < 16; ++kk) {
                float4 hvv = hs[ln * 17 + kk];
#pragma unroll
                for (int dk = 0; dk < 4; ++dk) {
                    acc1 = fma4(f4c(hvv, dk), ws1[(kk * 4 + dk) * 10 + qq], acc1);
                }
            }
            int n = blockIdx.x * 16 + ln;
            reinterpret_cast<float4*>(out)[(size_t)n * 10 + qq] = acc1;
        }
    }
}

// ---------------- launch ----------------

extern "C" void kernel_launch(void* const* d_in, const int* in_sizes, int n_in,
                              void* d_out, int out_size, void* d_ws, size_t ws_size,
                              hipStream_t stream) {
    const float* x      = (const float*)d_in[0];
    const int*   ei     = (const int*)d_in[1];
    const float* fc0_w  = (const float*)d_in[2];
    const float* fc0_b  = (const float*)d_in[3];
    const float* fc1_w  = (const float*)d_in[4];
    const float* fc1_b  = (const float*)d_in[5];
    const float* conv_w = (const float*)d_in[6];
    const int* row = ei;
    const int* col = ei + N_EDGES;

    char* ws = (char*)d_ws;
    size_t off = 0;
    auto alloc = [&](size_t bytes) -> void* {
        void* p = ws + off;
        off += (bytes + 255) & ~(size_t)255;
        return p;
    };
    float* dinv   = (float*)alloc((size_t)N_NODES * 4);
    int*   cnt    = (int*)alloc((size_t)N_NODES * 4);
    int*   starts = (int*)alloc((size_t)(N_NODES + 1) * 4);
    int*   cursor = (int*)alloc((size_t)(N_NODES + 1) * 4);
    int2*  csr2   = (int2*)alloc((size_t)N_EDGES * 8);
    int*   bsum   = (int*)alloc(128 * 4);
    float* bufA   = (float*)alloc((size_t)N_NODES * 64 * 4);
    float* bufB   = (float*)alloc((size_t)N_NODES * 64 * 4);
    float* bufC   = (float*)alloc((size_t)N_NODES * 64 * 4);
    if (off > ws_size) return;

    const int NB1 = (N_NODES + 1023) / 1024;          // 98
    const int GN  = (N_NODES + 255) / 256;            // 391
    const int GE  = (N_EDGES + 255) / 256;            // 3125
    const int GMM = (N_NODES + 63) / 64;              // 1563 (fc0)
    const int GP  = (N_NODES * 16) / 256;             // 6250 (prop/propconv)

    // CSR build + degree
    k_zero_cnt<<<GN, 256, 0, stream>>>(cnt);
    k_count<<<GE, 256, 0, stream>>>(col, cnt);
    k_scan1<<<NB1, 256, 0, stream>>>(cnt, starts, bsum, dinv);
    k_scan2<<<1, 128, 0, stream>>>(bsum, NB1);
    k_scan3<<<NB1, 256, 0, stream>>>(starts, cursor, bsum);
    k_fill<<<GE, 256, 0, stream>>>(row, col, dinv, cursor, csr2);

    // fc0 -> bufA; prop0 -> bufC (= x0 and layer-1 input)
    k_fc0<<<GMM, 256, 0, stream>>>(x, fc0_w, fc0_b, bufA);
    k_prop0<<<GP, 256, 0, stream>>>(bufA, bufC, dinv, starts, csr2);

    const float betas[4] = {0.f, logf(0.5f / 2.f + 1.f), logf(0.5f / 3.f + 1.f), logf(0.5f / 4.f + 1.f)};

    // layer 1: bufC -> bufA ; layer 2: bufA -> bufB ; layer 3 (+fc1): bufB -> d_out
    k_propconv<false><<<GP, 256, 0, stream>>>(bufC, bufC, dinv, starts, csr2,
                                              conv_w + 1 * 4096, betas[1], nullptr, nullptr, bufA);
    k_propconv<false><<<GP, 256, 0, stream>>>(bufA, bufC, dinv, starts, csr2,
                                              conv_w + 2 * 4096, betas[2], nullptr, nullptr, bufB);
    k_propconv<true><<<GP, 256, 0, stream>>>(bufB, bufC, dinv, starts, csr2,
                                             conv_w + 3 * 4096, betas[3], fc1_w, fc1_b, (float*)d_out);
}

// Round 5
// 265.543 us; speedup vs baseline: 4.9154x; 1.1225x over previous
//
#include <hip/hip_runtime.h>
#include <hip/hip_fp16.h>

#define N_NODES 100000
#define N_EDGES 800000
// D_IN=128, D_H=64, N_CLS=40, L=4, ALPHA=0.1, THETA=0.5
// Propagated state is stored PRE-MULTIPLIED: h_pre[n] = dinv[n]*h[n], in fp16 (64 halves = 128B/row).
// Then prop(h)[c] = dinv[c] * (h_pre[c] + sum_src h_pre[src]) — unweighted gather, int-only CSR.

__device__ inline float4 f4zero() { return make_float4(0.f, 0.f, 0.f, 0.f); }

__device__ inline float4 fma4(float s, float4 w, float4 a) {
    a.x = fmaf(s, w.x, a.x); a.y = fmaf(s, w.y, a.y);
    a.z = fmaf(s, w.z, a.z); a.w = fmaf(s, w.w, a.w);
    return a;
}

__device__ inline float4 relu4(float4 a) {
    a.x = fmaxf(a.x, 0.f); a.y = fmaxf(a.y, 0.f);
    a.z = fmaxf(a.z, 0.f); a.w = fmaxf(a.w, 0.f);
    return a;
}

__device__ inline float f4c(const float4& v, int i) {
    return reinterpret_cast<const float*>(&v)[i];
}

__device__ inline uint4 pack8(const float f[8]) {
    union { uint4 u; __half2 h[4]; } r;
#pragma unroll
    for (int k = 0; k < 4; ++k) r.h[k] = __floats2half2_rn(f[2 * k], f[2 * k + 1]);
    return r.u;
}

__device__ inline void unpack8(uint4 u, float f[8]) {
    union { uint4 u4; __half2 h[4]; } d; d.u4 = u;
#pragma unroll
    for (int k = 0; k < 4; ++k) { float2 t = __half22float2(d.h[k]); f[2 * k] = t.x; f[2 * k + 1] = t.y; }
}

__device__ inline uint2 pack4h(float4 v) {
    union { uint2 u; __half2 h[2]; } r;
    r.h[0] = __floats2half2_rn(v.x, v.y);
    r.h[1] = __floats2half2_rn(v.z, v.w);
    return r.u;
}

// ---------------- CSR build ----------------

__global__ __launch_bounds__(256) void k_zero_cnt(int* __restrict__ cnt) {
    int i = blockIdx.x * 256 + threadIdx.x;
    if (i < N_NODES) cnt[i] = 0;
}

__global__ __launch_bounds__(256) void k_count(const int* __restrict__ col, int* __restrict__ cnt) {
    int e = blockIdx.x * 256 + threadIdx.x;
    if (e < N_EDGES) atomicAdd(&cnt[col[e]], 1);
}

// block-wise exclusive scan: 1024 items per 256-thread block; also emits dinv and rsq=1/dinv
__global__ __launch_bounds__(256) void k_scan1(const int* __restrict__ cnt, int* __restrict__ starts,
                                               int* __restrict__ bsum, float* __restrict__ dinv,
                                               float* __restrict__ rsq) {
    __shared__ int sh[256];
    int t = threadIdx.x, b = blockIdx.x;
    int base = b * 1024 + t * 4;
    int c0 = 0, c1 = 0, c2 = 0, c3 = 0;
    if (base + 3 < N_NODES) {
        int4 v = *reinterpret_cast<const int4*>(cnt + base);
        c0 = v.x; c1 = v.y; c2 = v.z; c3 = v.w;
    } else {
        if (base + 0 < N_NODES) c0 = cnt[base + 0];
        if (base + 1 < N_NODES) c1 = cnt[base + 1];
        if (base + 2 < N_NODES) c2 = cnt[base + 2];
    }
    if (base + 0 < N_NODES) { dinv[base + 0] = rsqrtf((float)c0 + 1.f); rsq[base + 0] = sqrtf((float)c0 + 1.f); }
    if (base + 1 < N_NODES) { dinv[base + 1] = rsqrtf((float)c1 + 1.f); rsq[base + 1] = sqrtf((float)c1 + 1.f); }
    if (base + 2 < N_NODES) { dinv[base + 2] = rsqrtf((float)c2 + 1.f); rsq[base + 2] = sqrtf((float)c2 + 1.f); }
    if (base + 3 < N_NODES) { dinv[base + 3] = rsqrtf((float)c3 + 1.f); rsq[base + 3] = sqrtf((float)c3 + 1.f); }
    int s = c0 + c1 + c2 + c3;
    sh[t] = s;
    __syncthreads();
    for (int off = 1; off < 256; off <<= 1) {
        int add = (t >= off) ? sh[t - off] : 0;
        __syncthreads();
        sh[t] += add;
        __syncthreads();
    }
    int excl = sh[t] - s;
    if (t == 255) bsum[b] = sh[t];
    int p = excl;
    if (base + 0 < N_NODES) starts[base + 0] = p; p += c0;
    if (base + 1 < N_NODES) starts[base + 1] = p; p += c1;
    if (base + 2 < N_NODES) starts[base + 2] = p; p += c2;
    if (base + 3 < N_NODES) starts[base + 3] = p;
}

__global__ __launch_bounds__(128) void k_scan2(int* __restrict__ bsum, int nb) {
    __shared__ int sh[128];
    int t = threadIdx.x;
    int v = (t < nb) ? bsum[t] : 0;
    sh[t] = v;
    __syncthreads();
    for (int off = 1; off < 128; off <<= 1) {
        int add = (t >= off) ? sh[t - off] : 0;
        __syncthreads();
        sh[t] += add;
        __syncthreads();
    }
    if (t < nb) bsum[t] = sh[t] - v;
}

__global__ __launch_bounds__(256) void k_scan3(int* __restrict__ starts, int* __restrict__ cursor,
                                               const int* __restrict__ bsum) {
    int t = threadIdx.x, b = blockIdx.x;
    int off = bsum[b];
    int base = b * 1024 + t * 4;
#pragma unroll
    for (int j = 0; j < 4; ++j) {
        int i = base + j;
        if (i < N_NODES) {
            int v = starts[i] + off;
            starts[i] = v;
            cursor[i] = v;
        }
    }
    if (b == 0 && t == 0) starts[N_NODES] = N_EDGES;
}

// plain int CSR (no weights needed — h_pre is pre-multiplied)
__global__ __launch_bounds__(256) void k_fill(const int* __restrict__ row, const int* __restrict__ col,
                                              int* __restrict__ cursor, int* __restrict__ csr) {
    int e = blockIdx.x * 256 + threadIdx.x;
    if (e < N_EDGES) {
        int c = col[e];
        int p = atomicAdd(&cursor[c], 1);
        csr[p] = row[e];
    }
}

// ---------------- fc0: h_pre0 = fp16(dinv * relu(x @ W0 + b0)), 128 -> 64 ----------------
__global__ __launch_bounds__(256, 2) void k_fc0(const float* __restrict__ x, const float* __restrict__ w,
                                                const float* __restrict__ bias, const float* __restrict__ dinv,
                                                uint2* __restrict__ out) {
    __shared__ float4 ws[2048];     // W: 128 rows x 16 float4 = 32KB
    __shared__ float4 xs[64 * 33];  // x tile: 64 rows x 32 float4, pad->33
    const float4* wg = reinterpret_cast<const float4*>(w);
    const float4* x4 = reinterpret_cast<const float4*>(x);
    int tid = threadIdx.x;
    int base = blockIdx.x * 64;
#pragma unroll
    for (int i = 0; i < 8; ++i) ws[tid + 256 * i] = wg[tid + 256 * i];
#pragma unroll
    for (int j = 0; j < 8; ++j) {
        int f = tid + 256 * j;
        int ln = f >> 5, c = f & 31;
        xs[ln * 33 + c] = (base + ln < N_NODES) ? x4[(size_t)(base + ln) * 32 + c] : f4zero();
    }
    __syncthreads();
    int q = tid & 15, lbase = (tid >> 4) * 4;
    float4 bv = reinterpret_cast<const float4*>(bias)[q];
    float4 a0 = bv, a1 = bv, a2 = bv, a3 = bv;
#pragma unroll 4
    for (int kk = 0; kk < 32; ++kk) {
        float4 x0v = xs[(lbase + 0) * 33 + kk];
        float4 x1v = xs[(lbase + 1) * 33 + kk];
        float4 x2v = xs[(lbase + 2) * 33 + kk];
        float4 x3v = xs[(lbase + 3) * 33 + kk];
#pragma unroll
        for (int dk = 0; dk < 4; ++dk) {
            float4 w4 = ws[(kk * 4 + dk) * 16 + q];
            a0 = fma4(f4c(x0v, dk), w4, a0);
            a1 = fma4(f4c(x1v, dk), w4, a1);
            a2 = fma4(f4c(x2v, dk), w4, a2);
            a3 = fma4(f4c(x3v, dk), w4, a3);
        }
    }
    int n = base + lbase;
#pragma unroll
    for (int i = 0; i < 4; ++i) {
        if (n + i < N_NODES) {
            float dc = dinv[n + i];
            float4 r = relu4((i == 0) ? a0 : (i == 1) ? a1 : (i == 2) ? a2 : a3);
            r.x *= dc; r.y *= dc; r.z *= dc; r.w *= dc;
            out[(size_t)(n + i) * 16 + q] = pack4h(r);
        }
    }
}

// ---------------- 8-wide unweighted fp16 gather ----------------
// lane q of a node reads uint4 (8 halves) at hp[src*8+q]; mask-fma for the clamped tail.
__device__ __forceinline__ void gather8(const uint4* __restrict__ hp, const int* __restrict__ csr,
                                        int s, int e, int q, float acc[8]) {
    int l = e - 1;
    for (int p = s; p < e; p += 8) {
        uint4 d[8];
        float wgt[8];
#pragma unroll
        for (int j = 0; j < 8; ++j) {
            int src = csr[min(p + j, l)];
            d[j] = hp[(size_t)src * 8 + q];
            wgt[j] = (p + j <= l) ? 1.f : 0.f;
        }
#pragma unroll
        for (int j = 0; j < 8; ++j) {
            const __half2* h2 = reinterpret_cast<const __half2*>(&d[j]);
#pragma unroll
            for (int k = 0; k < 4; ++k) {
                float2 f = __half22float2(h2[k]);
                acc[2 * k]     = fmaf(wgt[j], f.x, acc[2 * k]);
                acc[2 * k + 1] = fmaf(wgt[j], f.y, acc[2 * k + 1]);
            }
        }
    }
}

// ---------------- prop0: x0_pre = fp16(dinv * relu(dinv * (h_pre0[c] + sum h_pre0[src]))) ----------------
__global__ __launch_bounds__(256, 6) void k_prop0(const uint4* __restrict__ hp, uint4* __restrict__ x0p,
                                                  const float* __restrict__ dinv,
                                                  const int* __restrict__ starts, const int* __restrict__ csr) {
    int t = blockIdx.x * 256 + threadIdx.x;
    int node = t >> 3, q = t & 7;
    float acc[8];
    unpack8(hp[(size_t)node * 8 + q], acc);  // self term
    gather8(hp, csr, starts[node], starts[node + 1], q, acc);
    float dc = dinv[node];
    float o[8];
#pragma unroll
    for (int k = 0; k < 8; ++k) o[k] = dc * fmaxf(dc * acc[k], 0.f);
    x0p[(size_t)node * 8 + q] = pack8(o);
}

// ---------------- fused: prop + alpha-combine + conv [+ fc1] ----------------
// 256 threads = 32 nodes x 8 lanes; lane owns 8 feature cols (q*8..q*8+7)
template <bool FINAL>
__global__ __launch_bounds__(256, FINAL ? 3 : 4) void k_propconv(
    const uint4* __restrict__ hp_in, const uint4* __restrict__ x0p,
    const float* __restrict__ dinv, const float* __restrict__ rsq,
    const int* __restrict__ starts, const int* __restrict__ csr,
    const float* __restrict__ w, float beta,
    const float* __restrict__ w1, const float* __restrict__ b1,
    void* __restrict__ out) {
    __shared__ float ws[64 * 64];                       // conv W row-major [k][c], 16KB
    __shared__ float ms[32][65];                        // m tile, pad->65
    __shared__ float hs[FINAL ? 32 : 1][FINAL ? 65 : 1];
    __shared__ float ws1[FINAL ? 64 * 41 : 1];

    int tid = threadIdx.x;
    int nl = tid >> 3, q = tid & 7;
    int node = blockIdx.x * 32 + nl;

    // stage weights early; completes under the gather
    const float4* wg = reinterpret_cast<const float4*>(w);
    float4* wsv = reinterpret_cast<float4*>(ws);
#pragma unroll
    for (int i = 0; i < 4; ++i) wsv[tid + 256 * i] = wg[tid + 256 * i];
    if constexpr (FINAL) {
        for (int i = tid; i < 64 * 40; i += 256) {
            int k = i / 40, c = i - k * 40;
            ws1[k * 41 + c] = w1[i];
        }
    }

    float acc[8];
    unpack8(hp_in[(size_t)node * 8 + q], acc);  // self term
    gather8(hp_in, csr, starts[node], starts[node + 1], q, acc);

    float dc = dinv[node];
    float rs = rsq[node];
    float xq[8];
    unpack8(x0p[(size_t)node * 8 + q], xq);
    float m[8];
#pragma unroll
    for (int k = 0; k < 8; ++k) m[k] = 0.9f * dc * acc[k] + 0.1f * rs * xq[k];
#pragma unroll
    for (int k = 0; k < 8; ++k) ms[nl][q * 8 + k] = m[k];
    __syncthreads();

    float a[8] = {0.f, 0.f, 0.f, 0.f, 0.f, 0.f, 0.f, 0.f};
#pragma unroll 8
    for (int k = 0; k < 64; ++k) {
        float mv = ms[nl][k];  // broadcast within 8-lane group
        float4 wv0 = *reinterpret_cast<const float4*>(&ws[k * 64 + q * 8]);
        float4 wv1 = *reinterpret_cast<const float4*>(&ws[k * 64 + q * 8 + 4]);
        a[0] = fmaf(mv, wv0.x, a[0]); a[1] = fmaf(mv, wv0.y, a[1]);
        a[2] = fmaf(mv, wv0.z, a[2]); a[3] = fmaf(mv, wv0.w, a[3]);
        a[4] = fmaf(mv, wv1.x, a[4]); a[5] = fmaf(mv, wv1.y, a[5]);
        a[6] = fmaf(mv, wv1.z, a[6]); a[7] = fmaf(mv, wv1.w, a[7]);
    }
    float omb = 1.f - beta;
    float r[8];
#pragma unroll
    for (int k = 0; k < 8; ++k) r[k] = fmaxf(fmaf(omb, m[k], beta * a[k]), 0.f);

    if constexpr (!FINAL) {
        float o[8];
#pragma unroll
        for (int k = 0; k < 8; ++k) o[k] = dc * r[k];
        reinterpret_cast<uint4*>(out)[(size_t)node * 8 + q] = pack8(o);
    } else {
#pragma unroll
        for (int k = 0; k < 8; ++k) hs[nl][q * 8 + k] = r[k];
        __syncthreads();
        float acc1[5];
#pragma unroll
        for (int j = 0; j < 5; ++j) acc1[j] = b1[q * 5 + j];
#pragma unroll 8
        for (int k = 0; k < 64; ++k) {
            float hv = hs[nl][k];
#pragma unroll
            for (int j = 0; j < 5; ++j) acc1[j] = fmaf(hv, ws1[k * 41 + q * 5 + j], acc1[j]);
        }
        float* o = reinterpret_cast<float*>(out) + (size_t)node * 40 + q * 5;
#pragma unroll
        for (int j = 0; j < 5; ++j) o[j] = acc1[j];
    }
}

// ---------------- launch ----------------

extern "C" void kernel_launch(void* const* d_in, const int* in_sizes, int n_in,
                              void* d_out, int out_size, void* d_ws, size_t ws_size,
                              hipStream_t stream) {
    const float* x      = (const float*)d_in[0];
    const int*   ei     = (const int*)d_in[1];
    const float* fc0_w  = (const float*)d_in[2];
    const float* fc0_b  = (const float*)d_in[3];
    const float* fc1_w  = (const float*)d_in[4];
    const float* fc1_b  = (const float*)d_in[5];
    const float* conv_w = (const float*)d_in[6];
    const int* row = ei;
    const int* col = ei + N_EDGES;

    char* ws = (char*)d_ws;
    size_t off = 0;
    auto alloc = [&](size_t bytes) -> void* {
        void* p = ws + off;
        off += (bytes + 255) & ~(size_t)255;
        return p;
    };
    float* dinv   = (float*)alloc((size_t)N_NODES * 4);
    float* rsq    = (float*)alloc((size_t)N_NODES * 4);
    int*   cnt    = (int*)alloc((size_t)N_NODES * 4);
    int*   starts = (int*)alloc((size_t)(N_NODES + 1) * 4);
    int*   cursor = (int*)alloc((size_t)(N_NODES + 1) * 4);
    int*   csr    = (int*)alloc((size_t)N_EDGES * 4);
    int*   bsum   = (int*)alloc(128 * 4);
    uint4* hp0    = (uint4*)alloc((size_t)N_NODES * 128);  // fp16 h_pre, 128B/row
    uint4* x0p    = (uint4*)alloc((size_t)N_NODES * 128);
    uint4* hpA    = (uint4*)alloc((size_t)N_NODES * 128);
    uint4* hpB    = (uint4*)alloc((size_t)N_NODES * 128);
    if (off > ws_size) return;

    const int NB1 = (N_NODES + 1023) / 1024;          // 98
    const int GN  = (N_NODES + 255) / 256;            // 391
    const int GE  = (N_EDGES + 255) / 256;            // 3125
    const int GMM = (N_NODES + 63) / 64;              // 1563 (fc0)
    const int GP  = (N_NODES * 8) / 256;              // 3125 (prop0: 8 lanes/node)
    const int GPC = N_NODES / 32;                     // 3125 (propconv: 32 nodes/block)

    // CSR build + degree
    k_zero_cnt<<<GN, 256, 0, stream>>>(cnt);
    k_count<<<GE, 256, 0, stream>>>(col, cnt);
    k_scan1<<<NB1, 256, 0, stream>>>(cnt, starts, bsum, dinv, rsq);
    k_scan2<<<1, 128, 0, stream>>>(bsum, NB1);
    k_scan3<<<NB1, 256, 0, stream>>>(starts, cursor, bsum);
    k_fill<<<GE, 256, 0, stream>>>(row, col, cursor, csr);

    // fc0 -> hp0 (fp16 pre-multiplied); prop0 -> x0p
    k_fc0<<<GMM, 256, 0, stream>>>(x, fc0_w, fc0_b, dinv, (uint2*)hp0);
    k_prop0<<<GP, 256, 0, stream>>>(hp0, x0p, dinv, starts, csr);

    const float betas[4] = {0.f, logf(0.5f / 2.f + 1.f), logf(0.5f / 3.f + 1.f), logf(0.5f / 4.f + 1.f)};

    // layer 1: x0p -> hpA ; layer 2: hpA -> hpB ; layer 3 (+fc1): hpB -> d_out
    k_propconv<false><<<GPC, 256, 0, stream>>>(x0p, x0p, dinv, rsq, starts, csr,
                                               conv_w + 1 * 4096, betas[1], nullptr, nullptr, hpA);
    k_propconv<false><<<GPC, 256, 0, stream>>>(hpA, x0p, dinv, rsq, starts, csr,
                                               conv_w + 2 * 4096, betas[2], nullptr, nullptr, hpB);
    k_propconv<true><<<GPC, 256, 0, stream>>>(hpB, x0p, dinv, rsq, starts, csr,
                                              conv_w + 3 * 4096, betas[3], fc1_w, fc1_b, d_out);
}